// Round 1
// baseline (1555.871 us; speedup 1.0000x reference)
//
#include <hip/hip_runtime.h>
#include <float.h>

// MAM dense: C[m,n] = max_k(A[m,k]*W[n,k]) + min_k(A[m,k]*W[n,k]) + bias[n]
// plus argmax/argmin indices. VALU-bound (no MFMA path for max-plus semiring).
// Tiling: 64x64 block tile, 256 threads, 4x4 register tile per thread,
// LDS staged transposed [BK][BM] so inner reads are ds_read_b128.

#define BM 64
#define BN 64
#define BK 32

__global__ __launch_bounds__(256, 4)
void mam_dense_kernel(const float* __restrict__ A, const float* __restrict__ W,
                      const float* __restrict__ bias,
                      float* __restrict__ out_v, float* __restrict__ out_ax,
                      float* __restrict__ out_an, int M, int N, int K) {
  __shared__ __align__(16) float Als[BK][BM];
  __shared__ __align__(16) float Wls[BK][BN];

  const int tid = threadIdx.x;
  const int tx = tid & 15;   // n-dim thread coord
  const int ty = tid >> 4;   // m-dim thread coord
  const int m0 = blockIdx.y * BM;
  const int n0 = blockIdx.x * BN;

  float vmax[4][4], vmin[4][4];
  int imax[4][4], imin[4][4];
#pragma unroll
  for (int i = 0; i < 4; ++i)
#pragma unroll
    for (int j = 0; j < 4; ++j) {
      vmax[i][j] = -FLT_MAX;
      vmin[i][j] = FLT_MAX;
      imax[i][j] = 0;
      imin[i][j] = 0;
    }

  // Staging: each thread loads 2 float4 per array per chunk (coalesced 128B
  // per 8 lanes), scatters into transposed LDS [k][m].
  const int r = tid >> 3;  // 0..31 (row within tile)
  const int c = tid & 7;   // 0..7  (k-offset c*4)

  for (int kk = 0; kk < K; kk += BK) {
#pragma unroll
    for (int rr = 0; rr < 2; ++rr) {
      const int row = r + rr * 32;
      int gm = m0 + row; gm = gm < M ? gm : M - 1;  // clamp; epilogue guards
      const float4 va = *(const float4*)(A + (size_t)gm * K + kk + c * 4);
      Als[c * 4 + 0][row] = va.x;
      Als[c * 4 + 1][row] = va.y;
      Als[c * 4 + 2][row] = va.z;
      Als[c * 4 + 3][row] = va.w;
      int gn = n0 + row; gn = gn < N ? gn : N - 1;
      const float4 vw = *(const float4*)(W + (size_t)gn * K + kk + c * 4);
      Wls[c * 4 + 0][row] = vw.x;
      Wls[c * 4 + 1][row] = vw.y;
      Wls[c * 4 + 2][row] = vw.z;
      Wls[c * 4 + 3][row] = vw.w;
    }
    __syncthreads();

#pragma unroll 8
    for (int k = 0; k < BK; ++k) {
      const int kg = kk + k;
      const float4 av = *(const float4*)(&Als[k][ty * 4]);
      const float4 wv = *(const float4*)(&Wls[k][tx * 4]);
      const float a[4] = {av.x, av.y, av.z, av.w};
      const float w[4] = {wv.x, wv.y, wv.z, wv.w};
#pragma unroll
      for (int i = 0; i < 4; ++i)
#pragma unroll
        for (int j = 0; j < 4; ++j) {
          const float p = a[i] * w[j];
          // strict > / < : first-occurrence tie-break matches np.argmax/argmin
          if (p > vmax[i][j]) { vmax[i][j] = p; imax[i][j] = kg; }
          if (p < vmin[i][j]) { vmin[i][j] = p; imin[i][j] = kg; }
        }
    }
    __syncthreads();
  }

  const int gn = n0 + tx * 4;
  float4 bv = make_float4(0.f, 0.f, 0.f, 0.f);
  if (gn + 3 < N) bv = *(const float4*)(bias + gn);
#pragma unroll
  for (int i = 0; i < 4; ++i) {
    const int gm = m0 + ty * 4 + i;
    if (gm < M && gn + 3 < N) {
      const size_t base = (size_t)gm * N + gn;
      float4 o;
      o.x = vmax[i][0] + vmin[i][0] + bv.x;
      o.y = vmax[i][1] + vmin[i][1] + bv.y;
      o.z = vmax[i][2] + vmin[i][2] + bv.z;
      o.w = vmax[i][3] + vmin[i][3] + bv.w;
      *(float4*)(out_v + base) = o;
      float4 ax;
      ax.x = (float)imax[i][0]; ax.y = (float)imax[i][1];
      ax.z = (float)imax[i][2]; ax.w = (float)imax[i][3];
      *(float4*)(out_ax + base) = ax;
      float4 an;
      an.x = (float)imin[i][0]; an.y = (float)imin[i][1];
      an.z = (float)imin[i][2]; an.w = (float)imin[i][3];
      *(float4*)(out_an + base) = an;
    }
  }
}

extern "C" void kernel_launch(void* const* d_in, const int* in_sizes, int n_in,
                              void* d_out, int out_size, void* d_ws, size_t ws_size,
                              hipStream_t stream) {
  const float* A = (const float*)d_in[0];     // [M, K] fp32
  const float* W = (const float*)d_in[1];     // [N, K] fp32
  const float* bias = (const float*)d_in[2];  // [N]    fp32
  const int N = in_sizes[2];
  const int K = in_sizes[1] / N;
  const int M = in_sizes[0] / K;
  float* out_v = (float*)d_out;                     // [M, N] fp32
  float* out_ax = out_v + (size_t)M * N;            // argmax as float
  float* out_an = out_v + 2 * (size_t)M * N;        // argmin as float
  dim3 grid((N + BN - 1) / BN, (M + BM - 1) / BM);
  mam_dense_kernel<<<grid, dim3(256), 0, stream>>>(A, W, bias, out_v, out_ax,
                                                   out_an, M, N, K);
}

// Round 2
// 1515.024 us; speedup vs baseline: 1.0270x; 1.0270x over previous
//
#include <hip/hip_runtime.h>
#include <float.h>

// MAM dense: C[m,n] = max_k(A[m,k]*W[n,k]) + min_k(A[m,k]*W[n,k]) + bias[n]
// plus argmax/argmin indices (first occurrence, strict >/< in ascending k).
// VALU-bound: ~7 VALU lane-ops per product (mul + 2x(cmp + 2 cndmask)).
// R1 lesson: __launch_bounds__(256,4) capped VGPRs at 64 -> accumulators
// lived in AGPRs -> v_accvgpr_read/write doubled VALU work (14.4/product
// measured). Fix: (256,2) so the 64 accumulator values stay in VGPRs.
// LDS pad +4 breaks the 8-way bank conflict on staging writes (bank was
// row%32 with only 8 distinct rows/wave); 68*4=272 is 16B-aligned so the
// ds_read_b128 fragment reads keep their alignment.

#define BM 64
#define BN 64
#define BK 32
#define LDP (BM + 4)   // padded leading dim

__global__ __launch_bounds__(256, 2)
void mam_dense_kernel(const float* __restrict__ A, const float* __restrict__ W,
                      const float* __restrict__ bias,
                      float* __restrict__ out_v, float* __restrict__ out_ax,
                      float* __restrict__ out_an, int M, int N, int K) {
  __shared__ __align__(16) float Als[BK][LDP];
  __shared__ __align__(16) float Wls[BK][LDP];

  const int tid = threadIdx.x;
  const int tx = tid & 15;   // n-dim thread coord
  const int ty = tid >> 4;   // m-dim thread coord
  const int m0 = blockIdx.y * BM;
  const int n0 = blockIdx.x * BN;

  float vmax[4][4], vmin[4][4];
  int imax[4][4], imin[4][4];
#pragma unroll
  for (int i = 0; i < 4; ++i)
#pragma unroll
    for (int j = 0; j < 4; ++j) {
      vmax[i][j] = -FLT_MAX;
      vmin[i][j] = FLT_MAX;
      imax[i][j] = 0;
      imin[i][j] = 0;
    }

  // Staging: each thread loads 2 float4 per array per chunk (coalesced 128B
  // per 8 lanes), scatters into transposed LDS [k][m] (padded).
  const int r = tid >> 3;  // 0..31 (row within tile)
  const int c = tid & 7;   // 0..7  (k-offset c*4)

  for (int kk = 0; kk < K; kk += BK) {
#pragma unroll
    for (int rr = 0; rr < 2; ++rr) {
      const int row = r + rr * 32;
      int gm = m0 + row; gm = gm < M ? gm : M - 1;  // clamp; epilogue guards
      const float4 va = *(const float4*)(A + (size_t)gm * K + kk + c * 4);
      Als[c * 4 + 0][row] = va.x;
      Als[c * 4 + 1][row] = va.y;
      Als[c * 4 + 2][row] = va.z;
      Als[c * 4 + 3][row] = va.w;
      int gn = n0 + row; gn = gn < N ? gn : N - 1;
      const float4 vw = *(const float4*)(W + (size_t)gn * K + kk + c * 4);
      Wls[c * 4 + 0][row] = vw.x;
      Wls[c * 4 + 1][row] = vw.y;
      Wls[c * 4 + 2][row] = vw.z;
      Wls[c * 4 + 3][row] = vw.w;
    }
    __syncthreads();

#pragma unroll 8
    for (int k = 0; k < BK; ++k) {
      const int kg = kk + k;
      const float4 av = *(const float4*)(&Als[k][ty * 4]);
      const float4 wv = *(const float4*)(&Wls[k][tx * 4]);
      const float a[4] = {av.x, av.y, av.z, av.w};
      const float w[4] = {wv.x, wv.y, wv.z, wv.w};
#pragma unroll
      for (int i = 0; i < 4; ++i)
#pragma unroll
        for (int j = 0; j < 4; ++j) {
          const float p = a[i] * w[j];
          // strict > / < : first-occurrence tie-break matches np.argmax/argmin
          if (p > vmax[i][j]) { vmax[i][j] = p; imax[i][j] = kg; }
          if (p < vmin[i][j]) { vmin[i][j] = p; imin[i][j] = kg; }
        }
    }
    __syncthreads();
  }

  const int gn = n0 + tx * 4;
  float4 bv = make_float4(0.f, 0.f, 0.f, 0.f);
  if (gn + 3 < N) bv = *(const float4*)(bias + gn);
#pragma unroll
  for (int i = 0; i < 4; ++i) {
    const int gm = m0 + ty * 4 + i;
    if (gm < M && gn + 3 < N) {
      const size_t base = (size_t)gm * N + gn;
      float4 o;
      o.x = vmax[i][0] + vmin[i][0] + bv.x;
      o.y = vmax[i][1] + vmin[i][1] + bv.y;
      o.z = vmax[i][2] + vmin[i][2] + bv.z;
      o.w = vmax[i][3] + vmin[i][3] + bv.w;
      *(float4*)(out_v + base) = o;
      float4 ax;
      ax.x = (float)imax[i][0]; ax.y = (float)imax[i][1];
      ax.z = (float)imax[i][2]; ax.w = (float)imax[i][3];
      *(float4*)(out_ax + base) = ax;
      float4 an;
      an.x = (float)imin[i][0]; an.y = (float)imin[i][1];
      an.z = (float)imin[i][2]; an.w = (float)imin[i][3];
      *(float4*)(out_an + base) = an;
    }
  }
}

extern "C" void kernel_launch(void* const* d_in, const int* in_sizes, int n_in,
                              void* d_out, int out_size, void* d_ws, size_t ws_size,
                              hipStream_t stream) {
  const float* A = (const float*)d_in[0];     // [M, K] fp32
  const float* W = (const float*)d_in[1];     // [N, K] fp32
  const float* bias = (const float*)d_in[2];  // [N]    fp32
  const int N = in_sizes[2];
  const int K = in_sizes[1] / N;
  const int M = in_sizes[0] / K;
  float* out_v = (float*)d_out;                     // [M, N] fp32
  float* out_ax = out_v + (size_t)M * N;            // argmax as float
  float* out_an = out_v + 2 * (size_t)M * N;        // argmin as float
  dim3 grid((N + BN - 1) / BN, (M + BM - 1) / BM);
  mam_dense_kernel<<<grid, dim3(256), 0, stream>>>(A, W, bias, out_v, out_ax,
                                                   out_an, M, N, K);
}